// Round 3
// baseline (3381.077 us; speedup 1.0000x reference)
//
#include <hip/hip_runtime.h>
#include <math.h>

#define HH 64
#define WWID 64
#define NB 4
constexpr int HW = HH * WWID;

// Fused 3x3 conv (stride1 pad1) + BN(inference) + ReLU.
// Block: 256 threads = 8 co_groups x 32 px_groups. Tile: (8*CPT) cout x 16x16 px.
// LDS input tile row-stride padded to 20 floats -> 16B-aligned float4 reads.
// Weights padded to 12 floats per (co,ci) -> float4-aligned, half-wave-uniform
// (broadcast) reads. Optional in2: input = in - in2 (conv5). Optional partial:
// per-block pixel-sum partials for fused global-avg-pool (out may be nullptr).
template<int CPT>
__global__ void __launch_bounds__(256)
conv3x3_bn_relu(const float* __restrict__ in, const float* __restrict__ in2,
                const float* __restrict__ wgt, const float* __restrict__ bn,
                float* __restrict__ out, float* __restrict__ partial,
                int Cin, int Co) {
  constexpr int CO_TILE = 8 * CPT;
  constexpr int CC = 8;  // Cin chunk per LDS stage
  __shared__ __align__(16) float s_in[CC][18 * 20];      // halo tile, stride 20
  __shared__ __align__(16) float s_w[CO_TILE * CC * 12]; // 12-float padded per (co,ci)

  const int t = threadIdx.x;
  const int pxt = blockIdx.x;   // 0..15 -> 16x16 pixel tile
  const int cot = blockIdx.y;
  const int b = blockIdx.z;
  const int h0 = (pxt >> 2) * 16, w0 = (pxt & 3) * 16;
  const int co_group = t >> 5, px_group = t & 31;
  const int r = px_group >> 1;            // row 0..15 in tile
  const int ch = (px_group & 1) * 8;      // col half: 0 or 8
  const int co0 = cot * CO_TILE + co_group * CPT;

  float acc[CPT][8];
  #pragma unroll
  for (int i = 0; i < CPT; ++i)
    #pragma unroll
    for (int j = 0; j < 8; ++j) acc[i][j] = 0.f;

  const float* inb = in + (size_t)b * Cin * HW;
  const float* inb2 = in2 ? in2 + (size_t)b * Cin * HW : nullptr;

  for (int ci0 = 0; ci0 < Cin; ci0 += CC) {
    __syncthreads();
    // stage input halo tile (zero-padded at image borders)
    for (int idx = t; idx < CC * 324; idx += 256) {
      int ci = idx / 324, rem = idx - ci * 324;
      int y = rem / 18, x = rem - y * 18;
      int gh = h0 - 1 + y, gw = w0 - 1 + x;
      float v = 0.f;
      if ((unsigned)gh < (unsigned)HH && (unsigned)gw < (unsigned)WWID) {
        size_t a = (size_t)(ci0 + ci) * HW + (size_t)gh * WWID + gw;
        v = inb[a];
        if (inb2) v -= inb2[a];
      }
      s_in[ci][y * 20 + x] = v;
    }
    // stage weights into padded co-major layout: s_w[co][ci][12], 9 used
    for (int idx = t; idx < CO_TILE * CC * 9; idx += 256) {
      int co = idx / (CC * 9), rr = idx - co * (CC * 9);
      int ci = rr / 9, k = rr - ci * 9;
      s_w[co * (CC * 12) + ci * 12 + k] =
          wgt[(size_t)(cot * CO_TILE + co) * Cin * 9 + (size_t)ci0 * 9 + rr];
    }
    __syncthreads();

    for (int ci = 0; ci < CC; ++ci) {
      // weights for this ci: CPT x 9, vector loads, uniform per half-wave
      float wv[CPT][9];
      #pragma unroll
      for (int i = 0; i < CPT; ++i) {
        const float* wp = &s_w[(co_group * CPT + i) * (CC * 12) + ci * 12];
        const float4 a0 = *reinterpret_cast<const float4*>(wp);
        const float4 a1 = *reinterpret_cast<const float4*>(wp + 4);
        wv[i][0] = a0.x; wv[i][1] = a0.y; wv[i][2] = a0.z; wv[i][3] = a0.w;
        wv[i][4] = a1.x; wv[i][5] = a1.y; wv[i][6] = a1.z; wv[i][7] = a1.w;
        wv[i][8] = wp[8];
      }
      #pragma unroll
      for (int kh = 0; kh < 3; ++kh) {
        // 10 input floats, 16B-aligned base -> b128/b128/b64
        const float* rp = &s_in[ci][(r + kh) * 20 + ch];
        const float4 r0 = *reinterpret_cast<const float4*>(rp);
        const float4 r1 = *reinterpret_cast<const float4*>(rp + 4);
        const float2 r2 = *reinterpret_cast<const float2*>(rp + 8);
        float row[10] = {r0.x, r0.y, r0.z, r0.w, r1.x, r1.y, r1.z, r1.w, r2.x, r2.y};
        #pragma unroll
        for (int kw = 0; kw < 3; ++kw)
          #pragma unroll
          for (int i = 0; i < CPT; ++i) {
            const float w = wv[i][kh * 3 + kw];
            #pragma unroll
            for (int j = 0; j < 8; ++j)
              acc[i][j] = fmaf(row[kw + j], w, acc[i][j]);
          }
      }
    }
  }

  // epilogue: BN + ReLU (+ optional store, + optional pixel-sum partial)
  float psum[CPT];
  #pragma unroll
  for (int i = 0; i < CPT; ++i) {
    int co = co0 + i;
    float g = bn[co], be = bn[Co + co], m = bn[2 * Co + co], v = bn[3 * Co + co];
    float scale = g / sqrtf(v + 1e-5f);
    float shift = be - m * scale;
    float s = 0.f;
    #pragma unroll
    for (int j = 0; j < 8; ++j) {
      float val = fmaf(acc[i][j], scale, shift);
      val = fmaxf(val, 0.f);
      if (out)
        out[(size_t)(b * Co + co) * HW + (size_t)(h0 + r) * WWID + (w0 + ch + j)] = val;
      s += val;
    }
    psum[i] = s;
  }
  if (partial) {
    #pragma unroll
    for (int i = 0; i < CPT; ++i) {
      float s = psum[i];
      #pragma unroll
      for (int off = 16; off > 0; off >>= 1) s += __shfl_down(s, off, 32);
      if (px_group == 0)
        partial[(size_t)(b * 256 + co0 + i) * 16 + pxt] = s;  // deterministic
    }
  }
}

// out[b,c,h,w] = sum_k atten[b,h,w,k] * x[b,c,h+dh,w+dw], 9x9 window, zero-pad.
// grid (h, b), 256 threads = 4 channel-groups x 64 w-lanes. x is L2-resident.
__global__ void __launch_bounds__(256)
weighting_kernel(const float* __restrict__ x, const float* __restrict__ atten,
                 float* __restrict__ out) {
  const int h = blockIdx.x, b = blockIdx.y;
  __shared__ float s_a[64 * 81];  // atten row for this (b,h), 20.7 KB
  const int t = threadIdx.x;
  for (int idx = t; idx < 64 * 81; idx += 256)
    s_a[idx] = atten[(size_t)((b * 64 + h) * 64) * 81 + idx];
  __syncthreads();

  const int w = t & 63, cg = t >> 6;  // lane = w -> coalesced x loads
  float acc[16];
  #pragma unroll
  for (int c = 0; c < 16; ++c) acc[c] = 0.f;

  for (int dh = -4; dh <= 4; ++dh) {
    int hh = h + dh;
    if ((unsigned)hh >= 64u) continue;  // block-uniform
    #pragma unroll
    for (int dw = -4; dw <= 4; ++dw) {
      int ww = w + dw;
      if ((unsigned)ww >= 64u) continue;  // per-lane, zero-pad
      float a = s_a[w * 81 + (dh + 4) * 9 + (dw + 4)];
      const float* xp = x + ((size_t)(b * 64 + cg * 16) * 64 + hh) * 64 + ww;
      #pragma unroll
      for (int c = 0; c < 16; ++c)
        acc[c] = fmaf(a, xp[(size_t)c * HW], acc[c]);
    }
  }
  float* op = out + ((size_t)(b * 64 + cg * 16) * 64 + h) * 64 + w;
  #pragma unroll
  for (int c = 0; c < 16; ++c) op[(size_t)c * HW] = acc[c];
}

// partial[4][256][16] -> pooled (mean) -> FC 256->10 -> 1. One block, wave per b.
__global__ void __launch_bounds__(256)
fc_kernel(const float* __restrict__ partial, const float* __restrict__ fw1,
          const float* __restrict__ fb1, const float* __restrict__ fw2,
          const float* __restrict__ fb2, float* __restrict__ outp) {
  const int t = threadIdx.x;
  const int b = t >> 6, lane = t & 63;
  float pooled[4];
  #pragma unroll
  for (int k = 0; k < 4; ++k) {
    int c = lane + 64 * k;
    float s = 0.f;
    #pragma unroll
    for (int p = 0; p < 16; ++p) s += partial[(size_t)(b * 256 + c) * 16 + p];
    pooled[k] = s * (1.f / 4096.f);
  }
  float o = 0.f;
  for (int i = 0; i < 10; ++i) {
    float d = 0.f;
    #pragma unroll
    for (int k = 0; k < 4; ++k) d += pooled[k] * fw1[i * 256 + lane + 64 * k];
    #pragma unroll
    for (int off = 32; off > 0; off >>= 1) d += __shfl_down(d, off, 64);
    o += (d + fb1[i]) * fw2[i];  // only lane 0's value matters
  }
  if (lane == 0) outp[b] = o + fb2[0];
}

extern "C" void kernel_launch(void* const* d_in, const int* in_sizes, int n_in,
                              void* d_out, int out_size, void* d_ws, size_t ws_size,
                              hipStream_t stream) {
  const float* low_key    = (const float*)d_in[0];
  const float* low_nonkey = (const float*)d_in[1];
  const float* atten      = (const float*)d_in[2];
  const float* w1 = (const float*)d_in[3];  const float* bn1 = (const float*)d_in[4];
  const float* w2 = (const float*)d_in[5];  const float* bn2 = (const float*)d_in[6];
  const float* w3 = (const float*)d_in[7];  const float* bn3 = (const float*)d_in[8];
  const float* w4 = (const float*)d_in[9];  const float* bn4 = (const float*)d_in[10];
  const float* w5 = (const float*)d_in[11]; const float* bn5 = (const float*)d_in[12];
  const float* fw1 = (const float*)d_in[13]; const float* fb1 = (const float*)d_in[14];
  const float* fw2 = (const float*)d_in[15]; const float* fb2 = (const float*)d_in[16];

  float* ws = (float*)d_ws;
  float* A  = ws;                 // 4*256*4096 = 4194304 (x1, later x4)
  float* Bb = A + 4194304;        // 4*64*4096  = 1048576 (x2)
  float* Cb = Bb + 1048576;       // 1048576 (x3)
  float* D  = Cb + 1048576;       // 4194304 (y)
  float* P  = D + 4194304;        // 4*256*16 = 16384 (pool partials)

  dim3 blk(256);
  // x1 = cbr(low_key, w1)            [4,256,64,64]
  conv3x3_bn_relu<4><<<dim3(16, 8, NB), blk, 0, stream>>>(low_key, nullptr, w1, bn1, A, nullptr, 1024, 256);
  // x2 = cbr(x1, w2)                 [4,64,64,64]
  conv3x3_bn_relu<2><<<dim3(16, 4, NB), blk, 0, stream>>>(A, nullptr, w2, bn2, Bb, nullptr, 256, 64);
  // x3 = weighting(x2, atten)
  weighting_kernel<<<dim3(64, NB), blk, 0, stream>>>(Bb, atten, Cb);
  // x4 = cbr(x3, w3)                 [4,256,64,64]  (reuses A; x1 dead)
  conv3x3_bn_relu<4><<<dim3(16, 8, NB), blk, 0, stream>>>(Cb, nullptr, w3, bn3, A, nullptr, 64, 256);
  // y = cbr(low_nonkey, w4)          [4,256,64,64]
  conv3x3_bn_relu<4><<<dim3(16, 8, NB), blk, 0, stream>>>(low_nonkey, nullptr, w4, bn4, D, nullptr, 1024, 256);
  // z = cbr(x4 - y, w5); fused global-avg-pool partials (no z materialized)
  conv3x3_bn_relu<4><<<dim3(16, 8, NB), blk, 0, stream>>>(A, D, w5, bn5, nullptr, P, 256, 256);
  // mean -> FC -> FC
  fc_kernel<<<1, 256, 0, stream>>>(P, fw1, fb1, fw2, fb2, (float*)d_out);
}

// Round 4
// 619.171 us; speedup vs baseline: 5.4607x; 5.4607x over previous
//
#include <hip/hip_runtime.h>
#include <math.h>

typedef _Float16 f16;
typedef f16 f16x8 __attribute__((ext_vector_type(8)));
typedef float f32x4 __attribute__((ext_vector_type(4)));

#define HH 64
#define WWID 64
#define NB 4
constexpr int HW = HH * WWID;

// Transpose + convert conv weights: w[co][ci][9] f32 -> wt[k][co][ci] f16.
__global__ void __launch_bounds__(256)
wtrans_kernel(const float* __restrict__ w, f16* __restrict__ wt, int Co, int Cin) {
  int idx = blockIdx.x * 256 + threadIdx.x;
  int total = Co * Cin * 9;
  if (idx >= total) return;
  int k = idx % 9, t2 = idx / 9;
  int ci = t2 % Cin, co = t2 / Cin;
  wt[((size_t)k * Co + co) * Cin + ci] = (f16)w[idx];
}

// Implicit-GEMM 3x3 conv + BN + ReLU, f16 MFMA 16x16x32, f32 accumulate.
// Tile: 64 co x 128 px (2 image rows). 4 waves in 2x2 grid; wave = 32co x 64px
// = 2(m) x 4(n) 16x16 frags. K = ci (chunks of 32) x 9 taps.
// A-frags: direct global dwordx4 from wt[tap][co][ci] (L2-resident).
// B: LDS xs[4 rows][66 w+halo][40 ci-pad] f16, ci contiguous for K-frags.
// in2 != null: input = in - in2 (conv5). out==null: emit pooled partials.
__global__ void __launch_bounds__(256)
conv_mfma(const float* __restrict__ in, const float* __restrict__ in2,
          const f16* __restrict__ wt, const float* __restrict__ bn,
          float* __restrict__ out, float* __restrict__ partial,
          int Cin, int Co) {
  __shared__ f16 xs[4][66][40];
  __shared__ float s_red[2][2][32];

  const int t = threadIdx.x;
  const int tile = blockIdx.x;          // 128 = 4b x 32 h-pairs
  const int b = tile >> 5;
  const int h0 = (tile & 31) * 2;
  const int co_blk = blockIdx.y * 64;
  const int wid = t >> 6, lane = t & 63;
  const int wave_m = wid >> 1, wave_n = wid & 1;
  const int l15 = lane & 15, lg = lane >> 4;
  const int koff = lg * 8;              // K offset within 32-ci chunk

  f32x4 acc[2][4];
  #pragma unroll
  for (int m = 0; m < 2; ++m)
    #pragma unroll
    for (int n = 0; n < 4; ++n)
      #pragma unroll
      for (int r = 0; r < 4; ++r) acc[m][n][r] = 0.f;

  const float* inb = in + (size_t)b * Cin * HW;
  const float* inb2 = in2 ? in2 + (size_t)b * Cin * HW : nullptr;

  // A fragment base: row co = co_blk + wave_m*32 + (m*16) + l15, k = koff+0..7
  const f16* wA = wt + (size_t)(co_blk + wave_m * 32 + l15) * Cin + koff;
  const size_t wTap = (size_t)Co * Cin;

  const f16* xsf = &xs[0][0][0];
  const int ldsbase = ((wave_n + 1) * 66 + l15 + 1) * 40 + koff;

  for (int ci0 = 0; ci0 < Cin; ci0 += 32) {
    __syncthreads();  // xs reusable (prev reads done)
    // zero the w-halo edge columns: 4r x 2 sides x 32ci = 256 slots
    {
      int r = t >> 6, side = (t >> 5) & 1, ci = t & 31;
      xs[r][side * 65][ci] = (f16)0.f;
    }
    // stage 4 rows x 32 ci: task = (r, ci-octet); lane covers w 0..63
    #pragma unroll
    for (int i = 0; i < 4; ++i) {
      int task = wid * 4 + i;
      int r = task >> 2, oct = task & 3;
      int gh = h0 - 1 + r;
      f16x8 v;
      if ((unsigned)gh < (unsigned)HH) {
        #pragma unroll
        for (int k = 0; k < 8; ++k) {
          size_t a = (size_t)(ci0 + oct * 8 + k) * HW + (size_t)gh * WWID + lane;
          float x = inb[a];
          if (inb2) x -= inb2[a];
          v[k] = (f16)x;
        }
      } else {
        #pragma unroll
        for (int k = 0; k < 8; ++k) v[k] = (f16)0.f;
      }
      *(f16x8*)&xs[r][lane + 1][oct * 8] = v;
    }
    __syncthreads();

    #pragma unroll
    for (int tap = 0; tap < 9; ++tap) {
      const int dh = tap / 3 - 1, dw = tap % 3 - 1;
      const f16* wp = wA + (size_t)tap * wTap + ci0;
      f16x8 a0 = *(const f16x8*)wp;
      f16x8 a1 = *(const f16x8*)(wp + (size_t)16 * Cin);
      const f16* bp = xsf + ldsbase + (dh * 66 + dw) * 40;
      #pragma unroll
      for (int n = 0; n < 4; ++n) {
        f16x8 bf = *(const f16x8*)(bp + n * 16 * 40);
        acc[0][n] = __builtin_amdgcn_mfma_f32_16x16x32_f16(a0, bf, acc[0][n], 0, 0, 0);
        acc[1][n] = __builtin_amdgcn_mfma_f32_16x16x32_f16(a1, bf, acc[1][n], 0, 0, 0);
      }
    }
  }

  // Epilogue: C/D frag: px col = l15 (+16n +64*wave_n), co row = lg*4+reg (+16m).
  if (out) {
    #pragma unroll
    for (int m = 0; m < 2; ++m)
      #pragma unroll
      for (int reg = 0; reg < 4; ++reg) {
        int co = co_blk + wave_m * 32 + m * 16 + lg * 4 + reg;
        float g = bn[co], be = bn[Co + co], mn = bn[2 * Co + co], vr = bn[3 * Co + co];
        float scale = g / sqrtf(vr + 1e-5f);
        float shift = be - mn * scale;
        float* op = out + ((size_t)(b * Co + co) * HH + (h0 + wave_n)) * WWID;
        #pragma unroll
        for (int n = 0; n < 4; ++n) {
          float val = fmaxf(fmaf(acc[m][n][reg], scale, shift), 0.f);
          op[n * 16 + l15] = val;
        }
      }
  } else {
    // conv5: BN+ReLU then pooled partial per (b,co,tile). Deterministic.
    #pragma unroll
    for (int m = 0; m < 2; ++m)
      #pragma unroll
      for (int reg = 0; reg < 4; ++reg) {
        int co = co_blk + wave_m * 32 + m * 16 + lg * 4 + reg;
        float g = bn[co], be = bn[Co + co], mn = bn[2 * Co + co], vr = bn[3 * Co + co];
        float scale = g / sqrtf(vr + 1e-5f);
        float shift = be - mn * scale;
        float s = 0.f;
        #pragma unroll
        for (int n = 0; n < 4; ++n)
          s += fmaxf(fmaf(acc[m][n][reg], scale, shift), 0.f);
        s += __shfl_xor(s, 1, 64);
        s += __shfl_xor(s, 2, 64);
        s += __shfl_xor(s, 4, 64);
        s += __shfl_xor(s, 8, 64);
        if (l15 == 0) s_red[wave_m][wave_n][m * 16 + lg * 4 + reg] = s;
      }
    __syncthreads();
    if (t < 64) {
      int wm = t >> 5, c32 = t & 31;
      float val = s_red[wm][0][c32] + s_red[wm][1][c32];
      int co = co_blk + wm * 32 + c32;
      partial[(size_t)(b * Co + co) * 32 + (tile & 31)] = val;
    }
  }
}

// out[b,c,h,w] = sum_k atten[b,h,w,k] * x[b,c,h+dh,w+dw], 9x9 window, zero-pad.
__global__ void __launch_bounds__(256)
weighting_kernel(const float* __restrict__ x, const float* __restrict__ atten,
                 float* __restrict__ out) {
  const int h = blockIdx.x, b = blockIdx.y;
  __shared__ float s_a[64 * 81];
  const int t = threadIdx.x;
  for (int idx = t; idx < 64 * 81; idx += 256)
    s_a[idx] = atten[(size_t)((b * 64 + h) * 64) * 81 + idx];
  __syncthreads();

  const int w = t & 63, cg = t >> 6;
  float acc[16];
  #pragma unroll
  for (int c = 0; c < 16; ++c) acc[c] = 0.f;

  for (int dh = -4; dh <= 4; ++dh) {
    int hh = h + dh;
    if ((unsigned)hh >= 64u) continue;
    #pragma unroll
    for (int dw = -4; dw <= 4; ++dw) {
      int ww = w + dw;
      if ((unsigned)ww >= 64u) continue;
      float a = s_a[w * 81 + (dh + 4) * 9 + (dw + 4)];
      const float* xp = x + ((size_t)(b * 64 + cg * 16) * 64 + hh) * 64 + ww;
      #pragma unroll
      for (int c = 0; c < 16; ++c)
        acc[c] = fmaf(a, xp[(size_t)c * HW], acc[c]);
    }
  }
  float* op = out + ((size_t)(b * 64 + cg * 16) * 64 + h) * 64 + w;
  #pragma unroll
  for (int c = 0; c < 16; ++c) op[(size_t)c * HW] = acc[c];
}

// partial[4][256][32] -> mean -> FC 256->10 -> 1. One block, wave per b.
__global__ void __launch_bounds__(256)
fc_kernel(const float* __restrict__ partial, const float* __restrict__ fw1,
          const float* __restrict__ fb1, const float* __restrict__ fw2,
          const float* __restrict__ fb2, float* __restrict__ outp) {
  const int t = threadIdx.x;
  const int b = t >> 6, lane = t & 63;
  float pooled[4];
  #pragma unroll
  for (int k = 0; k < 4; ++k) {
    int c = lane + 64 * k;
    float s = 0.f;
    #pragma unroll
    for (int p = 0; p < 32; ++p) s += partial[(size_t)(b * 256 + c) * 32 + p];
    pooled[k] = s * (1.f / 4096.f);
  }
  float o = 0.f;
  for (int i = 0; i < 10; ++i) {
    float d = 0.f;
    #pragma unroll
    for (int k = 0; k < 4; ++k) d += pooled[k] * fw1[i * 256 + lane + 64 * k];
    #pragma unroll
    for (int off = 32; off > 0; off >>= 1) d += __shfl_down(d, off, 64);
    o += (d + fb1[i]) * fw2[i];
  }
  if (lane == 0) outp[b] = o + fb2[0];
}

extern "C" void kernel_launch(void* const* d_in, const int* in_sizes, int n_in,
                              void* d_out, int out_size, void* d_ws, size_t ws_size,
                              hipStream_t stream) {
  const float* low_key    = (const float*)d_in[0];
  const float* low_nonkey = (const float*)d_in[1];
  const float* atten      = (const float*)d_in[2];
  const float* w1 = (const float*)d_in[3];  const float* bn1 = (const float*)d_in[4];
  const float* w2 = (const float*)d_in[5];  const float* bn2 = (const float*)d_in[6];
  const float* w3 = (const float*)d_in[7];  const float* bn3 = (const float*)d_in[8];
  const float* w4 = (const float*)d_in[9];  const float* bn4 = (const float*)d_in[10];
  const float* w5 = (const float*)d_in[11]; const float* bn5 = (const float*)d_in[12];
  const float* fw1 = (const float*)d_in[13]; const float* fb1 = (const float*)d_in[14];
  const float* fw2 = (const float*)d_in[15]; const float* fb2 = (const float*)d_in[16];

  float* ws = (float*)d_ws;
  float* A  = ws;                 // x1 / x4   [4,256,64,64]
  float* Bb = A + 4194304;        // x2        [4,64,64,64]
  float* Cb = Bb + 1048576;       // x3
  float* D  = Cb + 1048576;       // y
  float* P  = D + 4194304;        // partials [4][256][32]
  f16* wt1 = (f16*)(P + 32768);               // 9*256*1024
  f16* wt2 = wt1 + 2359296;                   // 9*64*256
  f16* wt3 = wt2 + 147456;                    // 9*256*64
  f16* wt4 = wt3 + 147456;                    // 9*256*1024
  f16* wt5 = wt4 + 2359296;                   // 9*256*256

  dim3 blk(256);
  // weight transforms (cheap, deterministic each call)
  wtrans_kernel<<<(256 * 1024 * 9 + 255) / 256, blk, 0, stream>>>(w1, wt1, 256, 1024);
  wtrans_kernel<<<(64 * 256 * 9 + 255) / 256, blk, 0, stream>>>(w2, wt2, 64, 256);
  wtrans_kernel<<<(256 * 64 * 9 + 255) / 256, blk, 0, stream>>>(w3, wt3, 256, 64);
  wtrans_kernel<<<(256 * 1024 * 9 + 255) / 256, blk, 0, stream>>>(w4, wt4, 256, 1024);
  wtrans_kernel<<<(256 * 256 * 9 + 255) / 256, blk, 0, stream>>>(w5, wt5, 256, 256);

  // x1 = cbr(low_key, w1)
  conv_mfma<<<dim3(128, 4), blk, 0, stream>>>(low_key, nullptr, wt1, bn1, A, nullptr, 1024, 256);
  // x2 = cbr(x1, w2)
  conv_mfma<<<dim3(128, 1), blk, 0, stream>>>(A, nullptr, wt2, bn2, Bb, nullptr, 256, 64);
  // x3 = weighting(x2, atten)
  weighting_kernel<<<dim3(64, NB), blk, 0, stream>>>(Bb, atten, Cb);
  // x4 = cbr(x3, w3)   (reuses A)
  conv_mfma<<<dim3(128, 4), blk, 0, stream>>>(Cb, nullptr, wt3, bn3, A, nullptr, 64, 256);
  // y = cbr(low_nonkey, w4)
  conv_mfma<<<dim3(128, 4), blk, 0, stream>>>(low_nonkey, nullptr, wt4, bn4, D, nullptr, 1024, 256);
  // z = cbr(x4 - y, w5) -> pooled partials
  conv_mfma<<<dim3(128, 4), blk, 0, stream>>>(A, D, wt5, bn5, nullptr, P, 256, 256);
  // mean -> FC -> FC
  fc_kernel<<<1, 256, 0, stream>>>(P, fw1, fb1, fw2, fb2, (float*)d_out);
}